// Round 9
// baseline (199.155 us; speedup 1.0000x reference)
//
#include <hip/hip_runtime.h>

// CharGRU2: 2-layer GRU (reset_after=true) + dense + softmax, fp32.
// B=2048, T=128, V=256, H=20, L=15.
//
// Round 9: UNIT-PER-LANE, 3 batches/wave. Lane 20g+j owns unit j of batch g
// and holds ALL THREE gate columns (j, j+20, j+40) of U0/W1/U1 (180 weight
// floats/lane, v2f-packed for v_pk_fma_f32). Consequences:
//   * z, r, h~, h-update are 100% lane-local -> ZERO bperm in the gate path
//     (R8 had 2 serial bperm levels + in-order lgkmcnt drain = ~1000 stall
//     cyc/step; R8 was latency-bound: VALUBusy 60%, wall unchanged).
//   * h replication for U-matvecs via per-group LDS broadcast: 2 ds_write +
//     10 ds_read_b128 per step, issued at loop top -> ONE ~120cyc exposure.
//   * fresh-h0 for xw1 via 20 group-local bperms (pipelined, one exposure).
//   * Every instruction serves 3 batches (SIMT amortization): per-batch
//     issue ~155 cyc/step vs R8's ~440.
// Register budget: amdgpu_waves_per_eu(1,1) -> 512 VGPRs/wave (R5 proved the
// attr is honored; R3 failed this layout only because launch_bounds(64,1)
// let the allocator chase occupancy and spill). ~240 live regs fit.
// 683 blocks x 64 threads = 1 wave/SIMD on 2/3 of SIMDs; the wave is
// self-overlapping (3 independent recurrences).

#define BB 2048
#define TT 128
#define HH 20
#define LL 15
#define H3 60

typedef float v2f __attribute__((ext_vector_type(2)));

__device__ __forceinline__ float bperm(int byteaddr, float v) {
    return __int_as_float(__builtin_amdgcn_ds_bpermute(byteaddr, __float_as_int(v)));
}
__device__ __forceinline__ float fast_rcp(float x) { return __builtin_amdgcn_rcpf(x); }
__device__ __forceinline__ float sigm(float x) { return fast_rcp(1.f + __expf(-x)); }
__device__ __forceinline__ float tanh_f(float x) { return 1.f - 2.f * fast_rcp(1.f + __expf(2.f * x)); }
#define PIN(v) asm volatile("" : "+v"(v))

extern "C" __global__ __launch_bounds__(64)
__attribute__((amdgpu_waves_per_eu(1, 1)))
void gru2_kernel(const int* __restrict__ x, const float* __restrict__ W0,
                 const float* __restrict__ U0, const float* __restrict__ b0i,
                 const float* __restrict__ b0r, const float* __restrict__ W1,
                 const float* __restrict__ U1, const float* __restrict__ b1i,
                 const float* __restrict__ b1r, const float* __restrict__ Wd,
                 const float* __restrict__ bd, float* __restrict__ out)
{
    const int lane = threadIdx.x;                        // one wave per block
    int g = lane / 20; if (g > 2) g = 2;                 // batch group 0..2
    int j = lane - g * 20; if (j > 19) j = 19;           // unit (lanes 60-63 dup)
    const int b  = blockIdx.x * 3 + g;
    const int bl = (b < BB) ? b : (BB - 1);
    const int gb4 = (g * 20) << 2;                       // group lane base, bytes

    const int c0 = j, c1 = j + 20, c2 = j + 40;          // this unit's 3 columns

    // ---- weights: 3 matrices x 3 cols x 10 k-pairs, pinned in VGPRs ----
    v2f u0z[10], u0r[10], u0h[10], w1z[10], w1r[10], w1h[10], u1z[10], u1r[10], u1h[10];
#pragma unroll
    for (int p = 0; p < 10; ++p) {
        const int k0 = (2 * p) * H3, k1 = (2 * p + 1) * H3;
        u0z[p] = v2f{U0[k0 + c0], U0[k1 + c0]};
        u0r[p] = v2f{U0[k0 + c1], U0[k1 + c1]};
        u0h[p] = v2f{U0[k0 + c2], U0[k1 + c2]};
        w1z[p] = v2f{W1[k0 + c0], W1[k1 + c0]};
        w1r[p] = v2f{W1[k0 + c1], W1[k1 + c1]};
        w1h[p] = v2f{W1[k0 + c2], W1[k1 + c2]};
        u1z[p] = v2f{U1[k0 + c0], U1[k1 + c0]};
        u1r[p] = v2f{U1[k0 + c1], U1[k1 + c1]};
        u1h[p] = v2f{U1[k0 + c2], U1[k1 + c2]};
    }
#pragma unroll
    for (int p = 0; p < 10; ++p) {
        PIN(u0z[p]); PIN(u0r[p]); PIN(u0h[p]);
        PIN(w1z[p]); PIN(w1r[p]); PIN(w1h[p]);
        PIN(u1z[p]); PIN(u1r[p]); PIN(u1h[p]);
    }
    float bi0z = b0i[c0], bi0r = b0i[c1], bi0h = b0i[c2];
    float br0z = b0r[c0], br0r = b0r[c1], br0h = b0r[c2];
    float bi1z = b1i[c0], bi1r = b1i[c1], bi1h = b1i[c2];
    float br1z = b1r[c0], br1r = b1r[c1], br1h = b1r[c2];
    PIN(bi0z); PIN(bi0r); PIN(bi0h); PIN(br0z); PIN(br0r); PIN(br0h);
    PIN(bi1z); PIN(bi1r); PIN(bi1h); PIN(br1z); PIN(br1r); PIN(br1h);

    // ---- per-group LDS staging of h0/h1 (24-float stride, 16B aligned) ----
    __shared__ __align__(16) float hb[3][2][24];
    float* h0buf = &hb[g][0][0];
    float* h1buf = &hb[g][1][0];
    h0buf[j] = 0.f; h1buf[j] = 0.f;                      // dup writes benign

    const int* xrow = x + bl * TT;

    float h0 = 0.f, h1 = 0.f;                            // unit j of batch g

    // ---- W0 pipeline: row t ready, row t+1 raw, token t+2 staged ----
    const int tok0 = xrow[0];
    const int tok1 = xrow[1];
    int tokn2 = xrow[2];
    float xz = W0[tok0 * H3 + c0] + bi0z;
    float xr = W0[tok0 * H3 + c1] + bi0r;
    float xh = W0[tok0 * H3 + c2] + bi0h;
    float nz = W0[tok1 * H3 + c0];
    float nr = W0[tok1 * H3 + c1];
    float nh = W0[tok1 * H3 + c2];

    for (int t = 0; t < TT; ++t) {
        // prefetch: W0 row for t+2 (token staged), token for t+3
        const int t3 = (t + 3 < TT) ? (t + 3) : (TT - 1);
        const float pz = W0[tokn2 * H3 + c0];
        const float pr = W0[tokn2 * H3 + c1];
        const float ph = W0[tokn2 * H3 + c2];
        const int tokn3 = xrow[t3];

        // ---- layer 0: rec0 = h0_staged @ U0 (+br0), 3 local chains ----
        const float4* h0q = (const float4*)h0buf;
        const float4* h1q = (const float4*)h1buf;        // issue both reads early
        v2f az = v2f{br0z, 0.f}, ar = v2f{br0r, 0.f}, ah = v2f{br0h, 0.f};
#pragma unroll
        for (int q = 0; q < 5; ++q) {
            const float4 hv = h0q[q];
            const v2f hA = v2f{hv.x, hv.y}, hB = v2f{hv.z, hv.w};
            az = __builtin_elementwise_fma(hA, u0z[2 * q], az);
            az = __builtin_elementwise_fma(hB, u0z[2 * q + 1], az);
            ar = __builtin_elementwise_fma(hA, u0r[2 * q], ar);
            ar = __builtin_elementwise_fma(hB, u0r[2 * q + 1], ar);
            ah = __builtin_elementwise_fma(hA, u0h[2 * q], ah);
            ah = __builtin_elementwise_fma(hB, u0h[2 * q + 1], ah);
        }
        // gates: fully lane-local
        const float z0  = sigm(xz + az.x + az.y);
        const float r0  = sigm(xr + ar.x + ar.y);
        const float hh0 = tanh_f(xh + r0 * (ah.x + ah.y));
        h0 = fmaf(z0, h0 - hh0, hh0);

        // stage h0 for next step's rec0 (off critical path)
        h0buf[j] = h0;

        // fresh h0 broadcast within group for xw1 (20 pipelined bperms)
        float hp[HH];
#pragma unroll
        for (int k = 0; k < HH; ++k) hp[k] = bperm(gb4 + (k << 2), h0);

        // ---- layer 1: rec1 from staged h1; xw1 from fresh h0 ----
        v2f bz = v2f{br1z, 0.f}, brv = v2f{br1r, 0.f}, bh = v2f{br1h, 0.f};
#pragma unroll
        for (int q = 0; q < 5; ++q) {
            const float4 hv = h1q[q];
            const v2f hA = v2f{hv.x, hv.y}, hB = v2f{hv.z, hv.w};
            bz  = __builtin_elementwise_fma(hA, u1z[2 * q], bz);
            bz  = __builtin_elementwise_fma(hB, u1z[2 * q + 1], bz);
            brv = __builtin_elementwise_fma(hA, u1r[2 * q], brv);
            brv = __builtin_elementwise_fma(hB, u1r[2 * q + 1], brv);
            bh  = __builtin_elementwise_fma(hA, u1h[2 * q], bh);
            bh  = __builtin_elementwise_fma(hB, u1h[2 * q + 1], bh);
        }
        v2f cz = v2f{bi1z, 0.f}, cr = v2f{bi1r, 0.f}, ch = v2f{bi1h, 0.f};
#pragma unroll
        for (int p = 0; p < 10; ++p) {
            const v2f hpp = v2f{hp[2 * p], hp[2 * p + 1]};
            cz = __builtin_elementwise_fma(hpp, w1z[p], cz);
            cr = __builtin_elementwise_fma(hpp, w1r[p], cr);
            ch = __builtin_elementwise_fma(hpp, w1h[p], ch);
        }
        const float z1  = sigm(cz.x + cz.y + bz.x + bz.y);
        const float r1  = sigm(cr.x + cr.y + brv.x + brv.y);
        const float hh1 = tanh_f(ch.x + ch.y + r1 * (bh.x + bh.y));
        h1 = fmaf(z1, h1 - hh1, hh1);

        // stage h1 for next step's rec1
        h1buf[j] = h1;

        // rotate W0 pipeline
        xz = nz + bi0z; xr = nr + bi0r; xh = nh + bi0h;
        nz = pz; nr = pr; nh = ph;
        tokn2 = tokn3;
    }

    // ---- dense (h1 @ Wd + bd) + softmax, within each 20-lane group ----
    float hq[HH];
#pragma unroll
    for (int k = 0; k < HH; ++k) hq[k] = bperm(gb4 + (k << 2), h1);
    const int l = (j < LL) ? j : (LL - 1);
    float acc = bd[l];
#pragma unroll
    for (int k = 0; k < HH; ++k) acc = fmaf(hq[k], Wd[k * LL + l], acc);

    float m = acc;
#pragma unroll
    for (int i = 0; i < LL; ++i) m = fmaxf(m, bperm(gb4 + (i << 2), acc));
    const float e = __expf(acc - m);
    float s = 0.f;
#pragma unroll
    for (int i = 0; i < LL; ++i) s += bperm(gb4 + (i << 2), e);
    const float p = e * fast_rcp(s);

    if (j < LL && b < BB && lane < H3) out[b * LL + j] = p;
}

extern "C" void kernel_launch(void* const* d_in, const int* in_sizes, int n_in,
                              void* d_out, int out_size, void* d_ws, size_t ws_size,
                              hipStream_t stream) {
    const int*   x   = (const int*)  d_in[0];
    const float* W0  = (const float*)d_in[1];
    const float* U0  = (const float*)d_in[2];
    const float* b0i = (const float*)d_in[3];
    const float* b0r = (const float*)d_in[4];
    const float* W1  = (const float*)d_in[5];
    const float* U1  = (const float*)d_in[6];
    const float* b1i = (const float*)d_in[7];
    const float* b1r = (const float*)d_in[8];
    const float* Wd  = (const float*)d_in[9];
    const float* bd  = (const float*)d_in[10];
    // d_in[11] = drop_rate (identity), unused
    float* out = (float*)d_out;

    // 3 batches/wave, 1 wave/block: ceil(2048/3) = 683 blocks.
    dim3 grid((BB + 2) / 3), block(64);
    hipLaunchKernelGGL(gru2_kernel, grid, block, 0, stream,
                       x, W0, U0, b0i, b0r, W1, U1, b1i, b1r, Wd, bd, out);
}

// Round 11
// 125.267 us; speedup vs baseline: 1.5898x; 1.5898x over previous
//
#include <hip/hip_runtime.h>

// CharGRU2: 2-layer GRU (reset_after=true) + dense + softmax, fp32.
// B=2048, T=128, V=256, H=20, L=15.
//
// Round 11 = R10 structure (cross-layer pipeline: iter i runs L0(t=i) +
// L1(t=i-1); all three dots rec0/xw1/rec1 off two 5x ds_read_b128 wave-
// uniform LDS broadcasts + pk_fma; zero readlane in loop) with two
// correctness fixes for R10's 6.8e-3 failure:
//
//  1. ROW-LOCAL DPP: R10 used wave_shr1 (0x138), whose cross-row behavior is
//     not reliable on CDNA4 — units straddling 16-lane row boundaries got
//     bound-zeroed gate hops. Now each DPP row holds 5 units at lanes
//     16r+3u+p (p=0:z 1:r 2:h~; lane 16r+15 idle-dup), and gate hops are
//     row_shr:1 (0x111) — core DPP mode, chains never cross a row.
//  2. LDS ORDER FENCES: asm volatile("" ::: "memory") after h0/h1 stores so
//     the float4 broadcast reads of the next iteration can never be hoisted
//     above them (vector-vs-float TBAA insurance).
// Home-lane guard excludes the idle dup lane (pos 15) from LDS writes.

#define BB 2048
#define TT 128
#define HH 20
#define LL 15
#define H3 60

typedef float v2f __attribute__((ext_vector_type(2)));

__device__ __forceinline__ float bclane(float v, int k) {
    return __int_as_float(__builtin_amdgcn_readlane(__float_as_int(v), k));
}
__device__ __forceinline__ float dpp_rshr1(float v) {
    // v_mov_b32_dpp row_shr:1 — lane i <- lane i-1 within its 16-lane row
    return __int_as_float(__builtin_amdgcn_update_dpp(
        0, __float_as_int(v), 0x111, 0xF, 0xF, true));
}
__device__ __forceinline__ float fast_rcp(float x) { return __builtin_amdgcn_rcpf(x); }
__device__ __forceinline__ float sigm(float x) { return fast_rcp(1.f + __expf(-x)); }
__device__ __forceinline__ float tanh_f(float x) { return 1.f - 2.f * fast_rcp(1.f + __expf(2.f * x)); }
#define PIN(v) asm volatile("" : "+v"(v))
#define LDSFENCE() asm volatile("" ::: "memory")

extern "C" __global__ __launch_bounds__(256)
__attribute__((amdgpu_waves_per_eu(2, 2)))
void gru2_kernel(const int* __restrict__ x, const float* __restrict__ W0,
                 const float* __restrict__ U0, const float* __restrict__ b0i,
                 const float* __restrict__ b0r, const float* __restrict__ W1,
                 const float* __restrict__ U1, const float* __restrict__ b1i,
                 const float* __restrict__ b1r, const float* __restrict__ Wd,
                 const float* __restrict__ bd, float* __restrict__ out)
{
    const int lane = threadIdx.x & 63;
    const int w = threadIdx.x >> 6;
    const int b = blockIdx.x * 4 + w;                    // batch = wave id
    const int row = lane >> 4;                           // DPP row 0..3
    const int pos = lane & 15;                           // pos in row
    const int pc  = (pos < 15) ? pos : 14;               // lane 16r+15 dups pos 14
    const int u   = pc / 3;                              // unit-in-row 0..4
    const int p3  = pc % 3;                              // 0:z 1:r 2:h~
    const int j   = row * 5 + u;                         // unit 0..19
    const bool home = (pos < 15) && (p3 == 2);           // h-home lanes (20 of them)
    const int col = p3 * 20 + j;                         // owned gate column

    // per-wave LDS staging of h0/h1 (wave-uniform broadcast reads)
    __shared__ __align__(16) float hbuf[4][2][24];
    float* h0buf = &hbuf[w][0][0];
    float* h1buf = &hbuf[w][1][0];
    if (home) { h0buf[j] = 0.f; h1buf[j] = 0.f; }
    LDSFENCE();

    // ---- weight columns (k-pair packed) into VGPRs, pinned ----
    v2f u0p[10], w1p[10], u1p[10];
#pragma unroll
    for (int q = 0; q < 10; ++q) {
        const int k0 = (2 * q) * H3, k1 = (2 * q + 1) * H3;
        u0p[q] = v2f{U0[k0 + col], U0[k1 + col]};
        w1p[q] = v2f{W1[k0 + col], W1[k1 + col]};
        u1p[q] = v2f{U1[k0 + col], U1[k1 + col]};
    }
#pragma unroll
    for (int q = 0; q < 10; ++q) { PIN(u0p[q]); PIN(w1p[q]); PIN(u1p[q]); }
    float bi0 = b0i[col], br0 = b0r[col], bi1 = b1i[col], br1 = b1r[col];
    PIN(bi0); PIN(br0); PIN(bi1); PIN(br1);

    // ---- tokens ----
    const int* xrow = x + b * TT;
    const int tokA = xrow[lane];
    const int tokB = xrow[64 + lane];

    float h0 = 0.f, h1 = 0.f;                            // home lanes hold state

    // ---- W0 pipeline: row t ready, row t+1 raw, token t+2 staged ----
    const int tok0 = __builtin_amdgcn_readlane(tokA, 0);
    const int tok1 = __builtin_amdgcn_readlane(tokA, 1);
    int tokn2 = __builtin_amdgcn_readlane(tokA, 2);
    float xw_cur = W0[tok0 * H3 + col] + bi0;
    float xw_nxt = W0[tok1 * H3 + col];

    // ---- prologue: L0 for t=0 (h0_{-1}=0 -> rec0 = br0) ----
    {
        const float pf = W0[tokn2 * H3 + col];
        const int tokn3 = __builtin_amdgcn_readlane(tokA, 3);
        const float rec0 = br0;
        const float sg0 = sigm(xw_cur + rec0);           // z on p=0, r on p=1
        const float rv0 = dpp_rshr1(sg0);                // home <- r_j
        const float zv0 = dpp_rshr1(rv0);                // home <- z_j
        const float hh0 = tanh_f(xw_cur + rv0 * rec0);
        h0 = fmaf(zv0, h0 - hh0, hh0);
        if (home) h0buf[j] = h0;
        LDSFENCE();
        xw_cur = xw_nxt + bi0; xw_nxt = pf; tokn2 = tokn3;
    }

    // ---- main loop: i = 1..127, L0(t=i) + L1(t=i-1) ----
#pragma unroll 2
    for (int i = 1; i < TT; ++i) {
        const int t3 = (i + 3 < TT) ? (i + 3) : (TT - 1);
        const float pf = W0[tokn2 * H3 + col];
        const int tokn3 = __builtin_amdgcn_readlane(t3 < 64 ? tokA : tokB, t3 & 63);

        // broadcast reads: h0buf = h0_{i-1}, h1buf = h1_{i-2}
        const float4* h0q = (const float4*)h0buf;
        const float4* h1q = (const float4*)h1buf;
        v2f a0 = v2f{br0, 0.f};   // rec0 (L0 t=i)
        v2f a1 = v2f{bi1, 0.f};   // xw1  (L1 t=i-1)
        v2f a2 = v2f{br1, 0.f};   // rec1 (L1 t=i-1)
#pragma unroll
        for (int q = 0; q < 5; ++q) {
            const float4 hv0 = h0q[q];
            const float4 hv1 = h1q[q];
            const v2f hA = v2f{hv0.x, hv0.y}, hB = v2f{hv0.z, hv0.w};
            const v2f gA = v2f{hv1.x, hv1.y}, gB = v2f{hv1.z, hv1.w};
            a0 = __builtin_elementwise_fma(hA, u0p[2 * q], a0);
            a0 = __builtin_elementwise_fma(hB, u0p[2 * q + 1], a0);
            a1 = __builtin_elementwise_fma(hA, w1p[2 * q], a1);
            a1 = __builtin_elementwise_fma(hB, w1p[2 * q + 1], a1);
            a2 = __builtin_elementwise_fma(gA, u1p[2 * q], a2);
            a2 = __builtin_elementwise_fma(gB, u1p[2 * q + 1], a2);
        }
        const float rec0 = a0.x + a0.y;
        const float xw1  = a1.x + a1.y;
        const float rec1 = a2.x + a2.y;

        // ---- L0 gates (t=i): row-local DPP hops ----
        const float sg0 = sigm(xw_cur + rec0);
        const float rv0 = dpp_rshr1(sg0);
        const float zv0 = dpp_rshr1(rv0);
        const float hh0 = tanh_f(xw_cur + rv0 * rec0);
        h0 = fmaf(zv0, h0 - hh0, hh0);
        if (home) h0buf[j] = h0;                         // for next iter
        LDSFENCE();

        // ---- L1 gates (t=i-1): independent of L0 above ----
        const float sg1 = sigm(xw1 + rec1);
        const float rv1 = dpp_rshr1(sg1);
        const float zv1 = dpp_rshr1(rv1);
        const float hh1 = tanh_f(xw1 + rv1 * rec1);
        h1 = fmaf(zv1, h1 - hh1, hh1);
        if (home) h1buf[j] = h1;                         // for next iter
        LDSFENCE();

        // rotate W0 pipeline
        xw_cur = xw_nxt + bi0; xw_nxt = pf; tokn2 = tokn3;
    }

    // ---- epilogue: L1 for t=127 (h0buf = h0_127, h1buf = h1_126) ----
    {
        const float4* h0q = (const float4*)h0buf;
        const float4* h1q = (const float4*)h1buf;
        v2f a1 = v2f{bi1, 0.f}, a2 = v2f{br1, 0.f};
#pragma unroll
        for (int q = 0; q < 5; ++q) {
            const float4 hv0 = h0q[q];
            const float4 hv1 = h1q[q];
            a1 = __builtin_elementwise_fma(v2f{hv0.x, hv0.y}, w1p[2 * q], a1);
            a1 = __builtin_elementwise_fma(v2f{hv0.z, hv0.w}, w1p[2 * q + 1], a1);
            a2 = __builtin_elementwise_fma(v2f{hv1.x, hv1.y}, u1p[2 * q], a2);
            a2 = __builtin_elementwise_fma(v2f{hv1.z, hv1.w}, u1p[2 * q + 1], a2);
        }
        const float xw1 = a1.x + a1.y, rec1 = a2.x + a2.y;
        const float sg1 = sigm(xw1 + rec1);
        const float rv1 = dpp_rshr1(sg1);
        const float zv1 = dpp_rshr1(rv1);
        const float hh1 = tanh_f(xw1 + rv1 * rec1);
        h1 = fmaf(zv1, h1 - hh1, hh1);
        if (home) h1buf[j] = h1;                         // final h1
        LDSFENCE();
    }

    // ---- dense (h1 @ Wd + bd) + softmax, lanes 0..14 ----
    const int l = lane < LL ? lane : LL - 1;
    float acc = bd[l];
#pragma unroll
    for (int k = 0; k < HH; ++k)
        acc = fmaf(h1buf[k], Wd[k * LL + l], acc);       // LDS broadcast reads

    float m = acc;
#pragma unroll
    for (int i = 0; i < LL; ++i) m = fmaxf(m, bclane(acc, i));
    const float e = __expf(acc - m);
    float s = 0.f;
#pragma unroll
    for (int i = 0; i < LL; ++i) s += bclane(e, i);
    const float pr = e * fast_rcp(s);

    if (lane < LL) out[b * LL + lane] = pr;
}

extern "C" void kernel_launch(void* const* d_in, const int* in_sizes, int n_in,
                              void* d_out, int out_size, void* d_ws, size_t ws_size,
                              hipStream_t stream) {
    const int*   x   = (const int*)  d_in[0];
    const float* W0  = (const float*)d_in[1];
    const float* U0  = (const float*)d_in[2];
    const float* b0i = (const float*)d_in[3];
    const float* b0r = (const float*)d_in[4];
    const float* W1  = (const float*)d_in[5];
    const float* U1  = (const float*)d_in[6];
    const float* b1i = (const float*)d_in[7];
    const float* b1r = (const float*)d_in[8];
    const float* Wd  = (const float*)d_in[9];
    const float* bd  = (const float*)d_in[10];
    // d_in[11] = drop_rate (identity), unused
    float* out = (float*)d_out;

    // 1 batch/wave, 4 waves/block -> 512 blocks = 2 blocks/CU = 2 waves/SIMD.
    dim3 grid(BB / 4), block(256);
    hipLaunchKernelGGL(gru2_kernel, grid, block, 0, stream,
                       x, W0, U0, b0i, b0r, W1, U1, b1i, b1r, Wd, bd, out);
}

// Round 12
// 125.158 us; speedup vs baseline: 1.5912x; 1.0009x over previous
//
#include <hip/hip_runtime.h>

// CharGRU2: 2-layer GRU (reset_after=true) + dense + softmax, fp32.
// B=2048, T=128, V=256, H=20, L=15.
//
// Round 12 = R11 (cross-layer pipeline, row-local DPP gate hops, LDS h
// broadcast staging, pk_fma dots, 2 waves/SIMD) + latency surgery:
//
//  1. SOFTWARE-PIPELINED LDS h-READS: next iteration's h0 quads (c0[5]) are
//     read immediately after the h0-store (latency hides behind the L1 gate
//     block); h1 quads (c1[5]) right after the h1-store (hides behind W0
//     rotation + next iter's W0 prefetch + the c0-consuming FMA chains,
//     which execute first -> lgkmcnt ordering gives c1 extra slack). The
//     loop top computes all three dots straight from REGISTERS — R11
//     exposed ~120 cyc of ds_read latency every iteration at the loop top.
//  2. SPLIT ACCUMULATORS: each dot uses two 5-deep pk_fma chains (was one
//     10-deep) -> matvec dep chain ~50 -> ~28 cyc.
//
// Layout recap: lane 16r+3u+p owns gate column p*20+(5r+u) (p=0:z 1:r 2:h~);
// gate hops are two chained v_mov_dpp row_shr:1 (never cross a 16-lane row);
// lane 16r+15 idles (dups pos 14, excluded from LDS writes).

#define BB 2048
#define TT 128
#define HH 20
#define LL 15
#define H3 60

typedef float v2f __attribute__((ext_vector_type(2)));

__device__ __forceinline__ float bclane(float v, int k) {
    return __int_as_float(__builtin_amdgcn_readlane(__float_as_int(v), k));
}
__device__ __forceinline__ float dpp_rshr1(float v) {
    // v_mov_b32_dpp row_shr:1 — lane i <- lane i-1 within its 16-lane row
    return __int_as_float(__builtin_amdgcn_update_dpp(
        0, __float_as_int(v), 0x111, 0xF, 0xF, true));
}
__device__ __forceinline__ float fast_rcp(float x) { return __builtin_amdgcn_rcpf(x); }
__device__ __forceinline__ float sigm(float x) { return fast_rcp(1.f + __expf(-x)); }
__device__ __forceinline__ float tanh_f(float x) { return 1.f - 2.f * fast_rcp(1.f + __expf(2.f * x)); }
#define PIN(v) asm volatile("" : "+v"(v))
#define LDSFENCE() asm volatile("" ::: "memory")

extern "C" __global__ __launch_bounds__(256)
__attribute__((amdgpu_waves_per_eu(2, 2)))
void gru2_kernel(const int* __restrict__ x, const float* __restrict__ W0,
                 const float* __restrict__ U0, const float* __restrict__ b0i,
                 const float* __restrict__ b0r, const float* __restrict__ W1,
                 const float* __restrict__ U1, const float* __restrict__ b1i,
                 const float* __restrict__ b1r, const float* __restrict__ Wd,
                 const float* __restrict__ bd, float* __restrict__ out)
{
    const int lane = threadIdx.x & 63;
    const int w = threadIdx.x >> 6;
    const int b = blockIdx.x * 4 + w;                    // batch = wave id
    const int row = lane >> 4;                           // DPP row 0..3
    const int pos = lane & 15;                           // pos in row
    const int pc  = (pos < 15) ? pos : 14;               // lane 16r+15 dups pos 14
    const int u   = pc / 3;                              // unit-in-row 0..4
    const int p3  = pc % 3;                              // 0:z 1:r 2:h~
    const int j   = row * 5 + u;                         // unit 0..19
    const bool home = (pos < 15) && (p3 == 2);           // 20 h-home lanes
    const int col = p3 * 20 + j;                         // owned gate column

    // per-wave LDS staging of h0/h1 (wave-uniform broadcast reads)
    __shared__ __align__(16) float hbuf[4][2][24];
    float* h0buf = &hbuf[w][0][0];
    float* h1buf = &hbuf[w][1][0];
    const float4* h0q = (const float4*)h0buf;
    const float4* h1q = (const float4*)h1buf;
    if (home) { h0buf[j] = 0.f; h1buf[j] = 0.f; }
    LDSFENCE();

    // ---- weight columns (k-pair packed) into VGPRs, pinned ----
    v2f u0p[10], w1p[10], u1p[10];
#pragma unroll
    for (int q = 0; q < 10; ++q) {
        const int k0 = (2 * q) * H3, k1 = (2 * q + 1) * H3;
        u0p[q] = v2f{U0[k0 + col], U0[k1 + col]};
        w1p[q] = v2f{W1[k0 + col], W1[k1 + col]};
        u1p[q] = v2f{U1[k0 + col], U1[k1 + col]};
    }
#pragma unroll
    for (int q = 0; q < 10; ++q) { PIN(u0p[q]); PIN(w1p[q]); PIN(u1p[q]); }
    float bi0 = b0i[col], br0 = b0r[col], bi1 = b1i[col], br1 = b1r[col];
    PIN(bi0); PIN(br0); PIN(bi1); PIN(br1);

    // ---- tokens ----
    const int* xrow = x + b * TT;
    const int tokA = xrow[lane];
    const int tokB = xrow[64 + lane];

    float h0 = 0.f, h1 = 0.f;                            // home lanes hold state

    // ---- W0 pipeline: row t ready, row t+1 raw, token t+2 staged ----
    const int tok0 = __builtin_amdgcn_readlane(tokA, 0);
    const int tok1 = __builtin_amdgcn_readlane(tokA, 1);
    int tokn2 = __builtin_amdgcn_readlane(tokA, 2);
    float xw_cur = W0[tok0 * H3 + col] + bi0;
    float xw_nxt = W0[tok1 * H3 + col];

    float4 c0[5], c1[5];                                 // register-staged h quads

    // ---- prologue: L0 for t=0 (h0_{-1}=0 -> rec0 = br0) ----
    {
        const float pf = W0[tokn2 * H3 + col];
        const int tokn3 = __builtin_amdgcn_readlane(tokA, 3);
        const float rec0 = br0;
        const float sg0 = sigm(xw_cur + rec0);           // z on p=0, r on p=1
        const float rv0 = dpp_rshr1(sg0);                // home <- r_j
        const float zv0 = dpp_rshr1(rv0);                // home <- z_j
        const float hh0 = tanh_f(xw_cur + rv0 * rec0);
        h0 = fmaf(zv0, h0 - hh0, hh0);
        if (home) h0buf[j] = h0;
        LDSFENCE();
#pragma unroll
        for (int q = 0; q < 5; ++q) { c0[q] = h0q[q]; c1[q] = h1q[q]; }
        xw_cur = xw_nxt + bi0; xw_nxt = pf; tokn2 = tokn3;
    }

    // ---- main loop: i = 1..127, L0(t=i) + L1(t=i-1); dots from registers ----
#pragma unroll 2
    for (int i = 1; i < TT; ++i) {
        const int t3 = (i + 3 < TT) ? (i + 3) : (TT - 1);
        const float pf = W0[tokn2 * H3 + col];
        const int tokn3 = __builtin_amdgcn_readlane(t3 < 64 ? tokA : tokB, t3 & 63);

        // c0 = h0_{i-1}, c1 = h1_{i-2}; two 5-deep chains per dot
        v2f a0a = v2f{br0, 0.f}, a0b = v2f{0.f, 0.f};    // rec0 (L0 t=i)
        v2f a1a = v2f{bi1, 0.f}, a1b = v2f{0.f, 0.f};    // xw1  (L1 t=i-1)
        v2f a2a = v2f{br1, 0.f}, a2b = v2f{0.f, 0.f};    // rec1 (L1 t=i-1)
#pragma unroll
        for (int q = 0; q < 5; ++q) {
            const v2f hA = v2f{c0[q].x, c0[q].y}, hB = v2f{c0[q].z, c0[q].w};
            a0a = __builtin_elementwise_fma(hA, u0p[2 * q], a0a);
            a0b = __builtin_elementwise_fma(hB, u0p[2 * q + 1], a0b);
            a1a = __builtin_elementwise_fma(hA, w1p[2 * q], a1a);
            a1b = __builtin_elementwise_fma(hB, w1p[2 * q + 1], a1b);
        }
#pragma unroll
        for (int q = 0; q < 5; ++q) {
            const v2f gA = v2f{c1[q].x, c1[q].y}, gB = v2f{c1[q].z, c1[q].w};
            a2a = __builtin_elementwise_fma(gA, u1p[2 * q], a2a);
            a2b = __builtin_elementwise_fma(gB, u1p[2 * q + 1], a2b);
        }
        const float rec0 = (a0a.x + a0a.y) + (a0b.x + a0b.y);
        const float xw1  = (a1a.x + a1a.y) + (a1b.x + a1b.y);
        const float rec1 = (a2a.x + a2a.y) + (a2b.x + a2b.y);

        // ---- L0 gates (t=i): row-local DPP hops ----
        const float sg0 = sigm(xw_cur + rec0);
        const float rv0 = dpp_rshr1(sg0);
        const float zv0 = dpp_rshr1(rv0);
        const float hh0 = tanh_f(xw_cur + rv0 * rec0);
        h0 = fmaf(zv0, h0 - hh0, hh0);
        if (home) h0buf[j] = h0;
        LDSFENCE();
        // prefetch next iter's h0 quads — latency hides behind L1 gates
#pragma unroll
        for (int q = 0; q < 5; ++q) c0[q] = h0q[q];

        // ---- L1 gates (t=i-1): independent of L0 above ----
        const float sg1 = sigm(xw1 + rec1);
        const float rv1 = dpp_rshr1(sg1);
        const float zv1 = dpp_rshr1(rv1);
        const float hh1 = tanh_f(xw1 + rv1 * rec1);
        h1 = fmaf(zv1, h1 - hh1, hh1);
        if (home) h1buf[j] = h1;
        LDSFENCE();
        // prefetch next iter's h1 quads — hides behind rotation + next c0-dots
#pragma unroll
        for (int q = 0; q < 5; ++q) c1[q] = h1q[q];

        // rotate W0 pipeline
        xw_cur = xw_nxt + bi0; xw_nxt = pf; tokn2 = tokn3;
    }

    // ---- epilogue: L1 for t=127 (c0 = h0_127, c1 = h1_126) ----
    {
        v2f a1a = v2f{bi1, 0.f}, a1b = v2f{0.f, 0.f};
        v2f a2a = v2f{br1, 0.f}, a2b = v2f{0.f, 0.f};
#pragma unroll
        for (int q = 0; q < 5; ++q) {
            const v2f hA = v2f{c0[q].x, c0[q].y}, hB = v2f{c0[q].z, c0[q].w};
            const v2f gA = v2f{c1[q].x, c1[q].y}, gB = v2f{c1[q].z, c1[q].w};
            a1a = __builtin_elementwise_fma(hA, w1p[2 * q], a1a);
            a1b = __builtin_elementwise_fma(hB, w1p[2 * q + 1], a1b);
            a2a = __builtin_elementwise_fma(gA, u1p[2 * q], a2a);
            a2b = __builtin_elementwise_fma(gB, u1p[2 * q + 1], a2b);
        }
        const float xw1  = (a1a.x + a1a.y) + (a1b.x + a1b.y);
        const float rec1 = (a2a.x + a2a.y) + (a2b.x + a2b.y);
        const float sg1 = sigm(xw1 + rec1);
        const float rv1 = dpp_rshr1(sg1);
        const float zv1 = dpp_rshr1(rv1);
        const float hh1 = tanh_f(xw1 + rv1 * rec1);
        h1 = fmaf(zv1, h1 - hh1, hh1);
        if (home) h1buf[j] = h1;                         // final h1
        LDSFENCE();
    }

    // ---- dense (h1 @ Wd + bd) + softmax, lanes 0..14 ----
    const int l = lane < LL ? lane : LL - 1;
    float acc = bd[l];
#pragma unroll
    for (int k = 0; k < HH; ++k)
        acc = fmaf(h1buf[k], Wd[k * LL + l], acc);       // LDS broadcast reads

    float m = acc;
#pragma unroll
    for (int i = 0; i < LL; ++i) m = fmaxf(m, bclane(acc, i));
    const float e = __expf(acc - m);
    float s = 0.f;
#pragma unroll
    for (int i = 0; i < LL; ++i) s += bclane(e, i);
    const float pr = e * fast_rcp(s);

    if (lane < LL) out[b * LL + lane] = pr;
}

extern "C" void kernel_launch(void* const* d_in, const int* in_sizes, int n_in,
                              void* d_out, int out_size, void* d_ws, size_t ws_size,
                              hipStream_t stream) {
    const int*   x   = (const int*)  d_in[0];
    const float* W0  = (const float*)d_in[1];
    const float* U0  = (const float*)d_in[2];
    const float* b0i = (const float*)d_in[3];
    const float* b0r = (const float*)d_in[4];
    const float* W1  = (const float*)d_in[5];
    const float* U1  = (const float*)d_in[6];
    const float* b1i = (const float*)d_in[7];
    const float* b1r = (const float*)d_in[8];
    const float* Wd  = (const float*)d_in[9];
    const float* bd  = (const float*)d_in[10];
    // d_in[11] = drop_rate (identity), unused
    float* out = (float*)d_out;

    // 1 batch/wave, 4 waves/block -> 512 blocks = 2 blocks/CU = 2 waves/SIMD.
    dim3 grid(BB / 4), block(256);
    hipLaunchKernelGGL(gru2_kernel, grid, block, 0, stream,
                       x, W0, U0, b0i, b0r, W1, U1, b1i, b1r, Wd, bd, out);
}